// Round 6
// baseline (835.018 us; speedup 1.0000x reference)
//
#include <hip/hip_runtime.h>

typedef float  f32x4 __attribute__((ext_vector_type(4)));
typedef short  s16x8 __attribute__((ext_vector_type(8)));

#define MFMA16(a,b,c) __builtin_amdgcn_mfma_f32_16x16x32_bf16(a,b,c,0,0,0)

// B=4, N1=N2=4096, D=H=256. Inputs fp32, output fp32 (R5 post-mortem:
// bit-identical absmax across ws layouts + 0.3706 > max|ref| 0.3066 =>
// bf16-out written into an fp32 buffer; R3's NaN proves inputs aren't bf16).
static __device__ __forceinline__ unsigned short f2bf(float f){
    union { float f; unsigned int u; } x; x.f = f;
    unsigned int r = x.u + 0x7fffu + ((x.u >> 16) & 1u);   // RNE
    return (unsigned short)(r >> 16);
}

// ---------------- kernel 1: W^T -> bf16 ----------------
__global__ void wt_prep(const float* __restrict__ Wq, const float* __restrict__ Wk,
                        const float* __restrict__ Wv, unsigned short* __restrict__ wt){
    int n = blockIdx.x, p = blockIdx.y, k = threadIdx.x;
    const float* W = (p==0) ? Wq : ((p==1) ? Wk : Wv);
    wt[p*65536 + n*256 + k] = f2bf(W[k*256 + n]);
}

// -------- staging helper: x tile (64x256 fp32) -> bf16 LDS (stride 264) ------
static __device__ __forceinline__ void stage_x(const float* x, size_t row0,
                                               int tid, unsigned short* sX){
    const float* xg = x + row0*256;
    #pragma unroll
    for(int rr=0; rr<16; rr++){
        int c = tid + rr*256;            // 4096 float4 chunks
        int row = c>>6, cc = c&63;
        float4 f = *(const float4*)(xg + row*256 + cc*4);
        unsigned short* d = &sX[row*264 + cc*4];
        d[0]=f2bf(f.x); d[1]=f2bf(f.y); d[2]=f2bf(f.z); d[3]=f2bf(f.w);
    }
}

// ---------------- kernel 2a: Q projection (all batches) ----------------------
__global__ __launch_bounds__(256) void proj_q(const float* __restrict__ x1,
        const unsigned short* __restrict__ wt, const float* __restrict__ bq,
        unsigned short* __restrict__ qdst){
    const int rt = blockIdx.x;
    const int tid = threadIdx.x, w = tid>>6, lane = tid&63, quad = lane>>4, lq = lane&15;
    __shared__ __align__(16) unsigned short sX[64*264];
    stage_x(x1, (size_t)rt*64, tid, sX);
    __syncthreads();

    s16x8 a[8];
    #pragma unroll
    for(int ks=0; ks<8; ks++)
        a[ks] = *(const s16x8*)(&sX[(16*w+lq)*264 + ks*32 + quad*8]);

    f32x4 acc[16];
    #pragma unroll
    for(int t=0;t<16;t++) acc[t] = (f32x4)(0.0f);
    #pragma unroll
    for(int ks=0; ks<8; ks++){
        #pragma unroll
        for(int t=0; t<16; t++){
            s16x8 bf_ = *(const s16x8*)(wt + (16*t+lq)*256 + ks*32 + quad*8);
            acc[t] = MFMA16(a[ks], bf_, acc[t]);
        }
    }
    #pragma unroll
    for(int t=0;t<16;t++){
        float bvf = bq[16*t+lq];
        #pragma unroll
        for(int r=0;r<4;r++){
            int row = rt*64 + 16*w + 4*quad + r;      // C layout: row=4*quad+reg
            qdst[(size_t)row*256 + 16*t + lq] = f2bf(acc[t][r] + bvf);
        }
    }
}

// ---------------- kernel 2b: K/V projection for ONE batch --------------------
// grid (64, 2): blockIdx.y 0 = K (row-major local), 1 = V^T (local).
__global__ __launch_bounds__(256) void proj_kv(const float* __restrict__ x2,
        const unsigned short* __restrict__ wt, const float* __restrict__ bk,
        const float* __restrict__ bv,
        unsigned short* __restrict__ kdst, unsigned short* __restrict__ vtdst, int b){
    const int rt = blockIdx.x, p = blockIdx.y;
    const int tid = threadIdx.x, w = tid>>6, lane = tid&63, quad = lane>>4, lq = lane&15;
    __shared__ __align__(16) unsigned short sX[64*264];
    stage_x(x2, (size_t)b*4096 + rt*64, tid, sX);
    __syncthreads();

    s16x8 a[8];
    #pragma unroll
    for(int ks=0; ks<8; ks++)
        a[ks] = *(const s16x8*)(&sX[(16*w+lq)*264 + ks*32 + quad*8]);

    f32x4 acc[16];
    #pragma unroll
    for(int t=0;t<16;t++) acc[t] = (f32x4)(0.0f);
    const unsigned short* wtp = wt + (p+1)*65536;
    #pragma unroll
    for(int ks=0; ks<8; ks++){
        #pragma unroll
        for(int t=0; t<16; t++){
            s16x8 bf_ = *(const s16x8*)(wtp + (16*t+lq)*256 + ks*32 + quad*8);
            acc[t] = MFMA16(a[ks], bf_, acc[t]);
        }
    }
    if(p == 0){
        #pragma unroll
        for(int t=0;t<16;t++){
            float bvf = bk[16*t+lq];
            #pragma unroll
            for(int r=0;r<4;r++){
                int row = rt*64 + 16*w + 4*quad + r;   // batch-local row
                kdst[(size_t)row*256 + 16*t + lq] = f2bf(acc[t][r] + bvf);
            }
        }
    } else {
        __syncthreads();                               // done reading sX as A
        #pragma unroll
        for(int t=0;t<16;t++){
            float bvf = bv[16*t+lq];
            #pragma unroll
            for(int r=0;r<4;r++)
                sX[(16*w + 4*quad + r)*264 + 16*t + lq] = f2bf(acc[t][r] + bvf);
        }
        __syncthreads();
        int n0 = rt*64, h = tid;
        #pragma unroll
        for(int cc=0; cc<8; cc++){
            unsigned short e[8];
            #pragma unroll
            for(int j=0;j<8;j++) e[j] = sX[(cc*8+j)*264 + h];
            ushort4 u0, u1;
            u0.x=e[0]; u0.y=e[1]; u0.z=e[2]; u0.w=e[3];
            u1.x=e[4]; u1.y=e[5]; u1.z=e[6]; u1.w=e[7];
            unsigned short* dst = vtdst + (size_t)h*4096 + n0 + cc*8;
            *(ushort4*)(dst)     = u0;
            *(ushort4*)(dst + 4) = u1;
        }
    }
}

// ---------------- kernel 3: flash attention (no-max softmax) -----------------
// grid (128 qtiles, nb batches), 256 threads (4 waves). TM=32 Q rows/block,
// 64 K-tiles of 64. kb/vtb batch-local (bk_); mask/q/out global (b=b0+bk_).
__global__ __launch_bounds__(256,2) void attn(
        const unsigned short* __restrict__ qb, const unsigned short* __restrict__ kb,
        const unsigned short* __restrict__ vtb, const int* __restrict__ mask,
        float* __restrict__ out, int b0){
    const int qt = blockIdx.x, bk_ = blockIdx.y, b = b0 + bk_;
    const int tid = threadIdx.x, w = tid>>6, lane = tid&63, quad = lane>>4, lq = lane&15;
    const int qbase = qt*32;

    __shared__ __align__(16) unsigned short sK [64*264];
    __shared__ __align__(16) unsigned short sVt[256*72];
    __shared__ __align__(16) unsigned short sP [32*72];
    __shared__ float sRS[32];
    if(tid < 32) sRS[tid] = 0.0f;

    s16x8 qf[2][8];
    #pragma unroll
    for(int rg=0; rg<2; rg++){
        size_t row = (size_t)(b*4096 + qbase + 16*rg + lq);
        #pragma unroll
        for(int ks=0; ks<8; ks++)
            qf[rg][ks] = *(const s16x8*)(qb + row*256 + ks*32 + quad*8);
    }

    f32x4 oacc[2][4];
    #pragma unroll
    for(int rg=0;rg<2;rg++){
        #pragma unroll
        for(int t=0;t<4;t++) oacc[rg][t] = (f32x4)(0.0f);
    }
    float rsum[8];
    #pragma unroll
    for(int i=0;i<8;i++) rsum[i] = 0.0f;

    for(int kt=0; kt<64; kt++){
        const int n0 = kt*64;
        __syncthreads();
        {   // stage K tile (64x256) and Vt tile (256x64), batch-local
            const unsigned short* kg = kb + ((size_t)(bk_*4096) + n0)*256;
            #pragma unroll
            for(int rr=0; rr<8; rr++){
                int c = tid + rr*256;
                int row = c>>5, cc = c&31;
                *(uint4*)(&sK[row*264 + cc*8]) = *(const uint4*)(kg + row*256 + cc*8);
            }
            const unsigned short* vg = vtb + (size_t)bk_*1048576 + n0;
            #pragma unroll
            for(int rr=0; rr<8; rr++){
                int c = tid + rr*256;
                int h = c>>3, cc = c&7;
                *(uint4*)(&sVt[h*72 + cc*8]) = *(const uint4*)(vg + (size_t)h*4096 + cc*8);
            }
        }
        int mreg[2][4];
        {
            const int* mp = mask + ((size_t)(b*4096 + qbase))*4096 + n0;
            #pragma unroll
            for(int rg=0;rg<2;rg++){
                #pragma unroll
                for(int r=0;r<4;r++){
                    int n1 = 16*rg + 4*quad + r;
                    mreg[rg][r] = mp[(size_t)n1*4096 + 16*w + lq];
                }
            }
        }
        __syncthreads();
        // ---- S = Q K^T: wave w -> cols 16w..16w+15 ----
        f32x4 sacc[2];
        sacc[0] = (f32x4)(0.0f); sacc[1] = (f32x4)(0.0f);
        #pragma unroll
        for(int ks=0; ks<8; ks++){
            s16x8 bf_ = *(const s16x8*)(&sK[(16*w + lq)*264 + ks*32 + quad*8]);
            sacc[0] = MFMA16(qf[0][ks], bf_, sacc[0]);
            sacc[1] = MFMA16(qf[1][ks], bf_, sacc[1]);
        }
        // ---- mask + exp + P->LDS (C layout -> row-major) ----
        #pragma unroll
        for(int rg=0;rg<2;rg++){
            #pragma unroll
            for(int r=0;r<4;r++){
                float s  = sacc[rg][r] * 0.0625f;                 // 1/sqrt(256)
                float pv = (mreg[rg][r] > 0) ? __expf(s) : 1.0f;  // exp(1e-9)==1.0f
                rsum[rg*4+r] += pv;
                sP[(16*rg + 4*quad + r)*72 + 16*w + lq] = f2bf(pv);
            }
        }
        __syncthreads();
        // ---- O += P V: wave w -> out cols 64w..64w+63 ----
        #pragma unroll
        for(int ks=0; ks<2; ks++){
            s16x8 a0 = *(const s16x8*)(&sP[(     lq)*72 + ks*32 + quad*8]);
            s16x8 a1 = *(const s16x8*)(&sP[(16 + lq)*72 + ks*32 + quad*8]);
            #pragma unroll
            for(int t=0; t<4; t++){
                s16x8 bf_ = *(const s16x8*)(&sVt[(64*w + 16*t + lq)*72 + ks*32 + quad*8]);
                oacc[0][t] = MFMA16(a0, bf_, oacc[0][t]);
                oacc[1][t] = MFMA16(a1, bf_, oacc[1][t]);
            }
        }
    }
    #pragma unroll
    for(int i=0;i<8;i++){
        float v = rsum[i];
        v += __shfl_xor(v,1); v += __shfl_xor(v,2);
        v += __shfl_xor(v,4); v += __shfl_xor(v,8);
        if(lq == 0) atomicAdd(&sRS[16*(i>>2) + 4*quad + (i&3)], v);
    }
    __syncthreads();
    #pragma unroll
    for(int rg=0;rg<2;rg++){
        #pragma unroll
        for(int t=0;t<4;t++){
            #pragma unroll
            for(int r=0;r<4;r++){
                int rowl = 16*rg + 4*quad + r;
                int col  = 64*w + 16*t + lq;
                out[((size_t)(b*4096 + qbase + rowl))*256 + col] =
                    oacc[rg][t][r] / sRS[rowl];
            }
        }
    }
}

extern "C" void kernel_launch(void* const* d_in, const int* in_sizes, int n_in,
                              void* d_out, int out_size, void* d_ws, size_t ws_size,
                              hipStream_t stream){
    (void)in_sizes; (void)n_in; (void)out_size;
    const float* x1 = (const float*)d_in[0];
    const float* x2 = (const float*)d_in[1];
    const int*   mk = (const int*)  d_in[2];
    const float* Wq = (const float*)d_in[3];
    const float* bq = (const float*)d_in[4];
    const float* Wk = (const float*)d_in[5];
    const float* bk = (const float*)d_in[6];
    const float* Wv = (const float*)d_in[7];
    const float* bv = (const float*)d_in[8];
    float* out = (float*)d_out;
    char* ws = (char*)d_ws;

    // ws layout: wt 384K @0 | q 8M @393216 | k... | vt...
    unsigned short* wt = (unsigned short*)ws;
    unsigned short* qb = (unsigned short*)(ws + 393216);
    const size_t kvoff = 393216 + 8388608;          // 8781824

    wt_prep<<<dim3(256,3), 256, 0, stream>>>(Wq, Wk, Wv, wt);
    proj_q <<<256, 256, 0, stream>>>(x1, wt, bq, qb);

    if(ws_size >= kvoff + 16ull*1024*1024){
        // single-shot: k 8MB + vt 8MB (all 4 batches), one big attn launch
        unsigned short* kbuf = (unsigned short*)(ws + kvoff);
        unsigned short* vtbf = (unsigned short*)(ws + kvoff + 8388608);
        for(int b=0;b<4;b++)
            proj_kv<<<dim3(64,2), 256, 0, stream>>>(x2, wt, bk, bv,
                    kbuf + (size_t)b*1048576, vtbf + (size_t)b*1048576, b);
        attn<<<dim3(128,4), 256, 0, stream>>>(qb, kbuf, vtbf, mk, out, 0);
    } else {
        // per-batch: k 2MB + vt 2MB reused (needs ~12.4MB ws total)
        unsigned short* kbuf = (unsigned short*)(ws + kvoff);
        unsigned short* vtbf = (unsigned short*)(ws + kvoff + 2097152);
        for(int b=0;b<4;b++){
            proj_kv<<<dim3(64,2), 256, 0, stream>>>(x2, wt, bk, bv, kbuf, vtbf, b);
            attn<<<dim3(128,1), 256, 0, stream>>>(qb, kbuf, vtbf, mk, out, b);
        }
    }
}

// Round 8
// 805.444 us; speedup vs baseline: 1.0367x; 1.0367x over previous
//
#include <hip/hip_runtime.h>

typedef float  f32x4 __attribute__((ext_vector_type(4)));
typedef short  s16x8 __attribute__((ext_vector_type(8)));
typedef short  s16x4 __attribute__((ext_vector_type(4)));

#define MFMA16(a,b,c) __builtin_amdgcn_mfma_f32_16x16x32_bf16(a,b,c,0,0,0)

// 16x16x16 bf16 MFMA (v_mfma_f32_16x16x16_bf16, ISA §10; builtin is the
// gfx90a-era _1k name). Guarded: host pass doesn't see device builtins via
// __has_builtin, but never executes this either — stub keeps host parse happy.
static __device__ __forceinline__ f32x4 mfma_pv(s16x4 a, s16x4 b, f32x4 c){
#if defined(__HIP_DEVICE_COMPILE__)
    return __builtin_amdgcn_mfma_f32_16x16x16bf16_1k(a, b, c, 0, 0, 0);
#else
    (void)a; (void)b; return c;
#endif
}

// B=4, N1=N2=4096, D=H=256. Inputs fp32, output fp32.
static __device__ __forceinline__ unsigned short f2bf(float f){
    union { float f; unsigned int u; } x; x.f = f;
    unsigned int r = x.u + 0x7fffu + ((x.u >> 16) & 1u);   // RNE
    return (unsigned short)(r >> 16);
}

// ---------------- kernel 1: W^T -> bf16 ----------------
__global__ void wt_prep(const float* __restrict__ Wq, const float* __restrict__ Wk,
                        const float* __restrict__ Wv, unsigned short* __restrict__ wt){
    int n = blockIdx.x, p = blockIdx.y, k = threadIdx.x;
    const float* W = (p==0) ? Wq : ((p==1) ? Wk : Wv);
    wt[p*65536 + n*256 + k] = f2bf(W[k*256 + n]);
}

// -------- staging helper: x tile (64x256 fp32) -> bf16 LDS (stride 264) ------
static __device__ __forceinline__ void stage_x(const float* x, size_t row0,
                                               int tid, unsigned short* sX){
    const float* xg = x + row0*256;
    #pragma unroll
    for(int rr=0; rr<16; rr++){
        int c = tid + rr*256;
        int row = c>>6, cc = c&63;
        float4 f = *(const float4*)(xg + row*256 + cc*4);
        unsigned short* d = &sX[row*264 + cc*4];
        d[0]=f2bf(f.x); d[1]=f2bf(f.y); d[2]=f2bf(f.z); d[3]=f2bf(f.w);
    }
}

// ---------------- kernel 2a: Q projection (all batches) ----------------------
__global__ __launch_bounds__(256) void proj_q(const float* __restrict__ x1,
        const unsigned short* __restrict__ wt, const float* __restrict__ bq,
        unsigned short* __restrict__ qdst){
    const int rt = blockIdx.x;
    const int tid = threadIdx.x, w = tid>>6, lane = tid&63, quad = lane>>4, lq = lane&15;
    __shared__ __align__(16) unsigned short sX[64*264];
    stage_x(x1, (size_t)rt*64, tid, sX);
    __syncthreads();

    s16x8 a[8];
    #pragma unroll
    for(int ks=0; ks<8; ks++)
        a[ks] = *(const s16x8*)(&sX[(16*w+lq)*264 + ks*32 + quad*8]);

    f32x4 acc[16];
    #pragma unroll
    for(int t=0;t<16;t++) acc[t] = (f32x4)(0.0f);
    #pragma unroll
    for(int ks=0; ks<8; ks++){
        #pragma unroll
        for(int t=0; t<16; t++){
            s16x8 bf_ = *(const s16x8*)(wt + (16*t+lq)*256 + ks*32 + quad*8);
            acc[t] = MFMA16(a[ks], bf_, acc[t]);
        }
    }
    #pragma unroll
    for(int t=0;t<16;t++){
        float bvf = bq[16*t+lq];
        #pragma unroll
        for(int r=0;r<4;r++){
            int row = rt*64 + 16*w + 4*quad + r;      // C layout: row=4*quad+reg
            qdst[(size_t)row*256 + 16*t + lq] = f2bf(acc[t][r] + bvf);
        }
    }
}

// ---------------- kernel 2b: K/V projection for ONE batch --------------------
__global__ __launch_bounds__(256) void proj_kv(const float* __restrict__ x2,
        const unsigned short* __restrict__ wt, const float* __restrict__ bk,
        const float* __restrict__ bv,
        unsigned short* __restrict__ kdst, unsigned short* __restrict__ vtdst, int b){
    const int rt = blockIdx.x, p = blockIdx.y;
    const int tid = threadIdx.x, w = tid>>6, lane = tid&63, quad = lane>>4, lq = lane&15;
    __shared__ __align__(16) unsigned short sX[64*264];
    stage_x(x2, (size_t)b*4096 + rt*64, tid, sX);
    __syncthreads();

    s16x8 a[8];
    #pragma unroll
    for(int ks=0; ks<8; ks++)
        a[ks] = *(const s16x8*)(&sX[(16*w+lq)*264 + ks*32 + quad*8]);

    f32x4 acc[16];
    #pragma unroll
    for(int t=0;t<16;t++) acc[t] = (f32x4)(0.0f);
    const unsigned short* wtp = wt + (p+1)*65536;
    #pragma unroll
    for(int ks=0; ks<8; ks++){
        #pragma unroll
        for(int t=0; t<16; t++){
            s16x8 bf_ = *(const s16x8*)(wtp + (16*t+lq)*256 + ks*32 + quad*8);
            acc[t] = MFMA16(a[ks], bf_, acc[t]);
        }
    }
    if(p == 0){
        #pragma unroll
        for(int t=0;t<16;t++){
            float bvf = bk[16*t+lq];
            #pragma unroll
            for(int r=0;r<4;r++){
                int row = rt*64 + 16*w + 4*quad + r;   // batch-local row
                kdst[(size_t)row*256 + 16*t + lq] = f2bf(acc[t][r] + bvf);
            }
        }
    } else {
        __syncthreads();
        #pragma unroll
        for(int t=0;t<16;t++){
            float bvf = bv[16*t+lq];
            #pragma unroll
            for(int r=0;r<4;r++)
                sX[(16*w + 4*quad + r)*264 + 16*t + lq] = f2bf(acc[t][r] + bvf);
        }
        __syncthreads();
        int n0 = rt*64, h = tid;
        #pragma unroll
        for(int cc=0; cc<8; cc++){
            unsigned short e[8];
            #pragma unroll
            for(int j=0;j<8;j++) e[j] = sX[(cc*8+j)*264 + h];
            ushort4 u0, u1;
            u0.x=e[0]; u0.y=e[1]; u0.z=e[2]; u0.w=e[3];
            u1.x=e[4]; u1.y=e[5]; u1.z=e[6]; u1.w=e[7];
            unsigned short* dst = vtdst + (size_t)h*4096 + n0 + cc*8;
            *(ushort4*)(dst)     = u0;
            *(ushort4*)(dst + 4) = u1;
        }
    }
}

// ---------------- kernel 3: barrier-free flash attention ---------------------
// grid (128 qtiles, nb), 256 threads (4 waves). TM=32 q-rows/block, kt loop
// over 64 tiles of TN=64; wave w owns n2-subslice [64kt+16w, +16).
// S^T = MFMA(A=K, B=Q): C gives P^T[n2local=4quad+r][q=lq] == B-layout of the
// 16x16x16 MFMA (k=4quad+j), so PV (O^T += V^T @ P^T) runs straight from regs.
// Each wave accumulates a private partial O^T[256][32] (k-split), reduced
// across waves in LDS once at the end. NO barriers / LDS in the main loop.
__global__ __launch_bounds__(256,2) void attn(
        const unsigned short* __restrict__ qb, const unsigned short* __restrict__ kb,
        const unsigned short* __restrict__ vtb, const int* __restrict__ mask,
        float* __restrict__ out, int b0){
    const int qt = blockIdx.x, bk_ = blockIdx.y, b = b0 + bk_;
    const int tid = threadIdx.x, w = tid>>6, lane = tid&63, quad = lane>>4, lq = lane&15;
    const int qbase = qt*32;

    __shared__ float sRS[4][32];
    __shared__ float sRed[4][32*65 + 1];   // [w][q*65 + hl], pad to dodge bank hits

    // Q as B-operand frags: B[k=32ks+8quad+j][n=q=lq], rows qbase+16rg+lq
    s16x8 qf[2][8];
    #pragma unroll
    for(int rg=0; rg<2; rg++){
        size_t row = (size_t)(b*4096 + qbase + 16*rg + lq);
        #pragma unroll
        for(int ks=0; ks<8; ks++)
            qf[rg][ks] = *(const s16x8*)(qb + row*256 + ks*32 + quad*8);
    }

    f32x4 oacc[16][2];                     // O^T partial: h=16t+4quad+r, q=16rg+lq
    #pragma unroll
    for(int t=0;t<16;t++){ oacc[t][0] = (f32x4)(0.0f); oacc[t][1] = (f32x4)(0.0f); }
    float rsum[2] = {0.0f, 0.0f};

    const unsigned short* kp0 = kb  + ((size_t)bk_*4096 + 16*w + lq)*256 + 8*quad;
    const unsigned short* vp0 = vtb + ((size_t)bk_*256  + lq)*4096 + 16*w + 4*quad;
    const int*            mp0 = mask + ((size_t)(b*4096 + qbase) + lq)*4096 + 16*w + 4*quad;

    for(int kt=0; kt<64; kt++){
        // K A-frags: A[m=n2=16w+lq][k=32ks+8quad+j]
        const unsigned short* kp = kp0 + (size_t)kt*64*256;
        s16x8 kf[8];
        #pragma unroll
        for(int ks=0; ks<8; ks++) kf[ks] = *(const s16x8*)(kp + 32*ks);
        // mask: rows qbase+16rg+lq, cols 64kt+16w+4quad+[0..3]
        int4 m0 = *(const int4*)(mp0 + kt*64);
        int4 m1 = *(const int4*)(mp0 + 16*4096 + kt*64);
        // S^T: D[n2local=4quad+r][q=lq]
        f32x4 sacc0 = (f32x4)(0.0f), sacc1 = (f32x4)(0.0f);
        #pragma unroll
        for(int ks=0; ks<8; ks++){
            sacc0 = MFMA16(kf[ks], qf[0][ks], sacc0);
            sacc1 = MFMA16(kf[ks], qf[1][ks], sacc1);
        }
        // mask + exp + pack to PV B-frags (k=4quad+j == C rows 4quad+r)
        s16x4 pb0, pb1;
        {
            float p;
            p = (m0.x>0)?__expf(sacc0[0]*0.0625f):1.0f; rsum[0]+=p; pb0[0]=(short)f2bf(p);
            p = (m0.y>0)?__expf(sacc0[1]*0.0625f):1.0f; rsum[0]+=p; pb0[1]=(short)f2bf(p);
            p = (m0.z>0)?__expf(sacc0[2]*0.0625f):1.0f; rsum[0]+=p; pb0[2]=(short)f2bf(p);
            p = (m0.w>0)?__expf(sacc0[3]*0.0625f):1.0f; rsum[0]+=p; pb0[3]=(short)f2bf(p);
            p = (m1.x>0)?__expf(sacc1[0]*0.0625f):1.0f; rsum[1]+=p; pb1[0]=(short)f2bf(p);
            p = (m1.y>0)?__expf(sacc1[1]*0.0625f):1.0f; rsum[1]+=p; pb1[1]=(short)f2bf(p);
            p = (m1.z>0)?__expf(sacc1[2]*0.0625f):1.0f; rsum[1]+=p; pb1[2]=(short)f2bf(p);
            p = (m1.w>0)?__expf(sacc1[3]*0.0625f):1.0f; rsum[1]+=p; pb1[3]=(short)f2bf(p);
        }
        // PV: O^T[h][q] += V^T[h][n2slice] * P^T; A=V^T[m=h=16t+lq][k=4quad+j]
        const unsigned short* vp = vp0 + kt*64;
        #pragma unroll
        for(int t=0; t<16; t++){
            s16x4 vf = *(const s16x4*)(vp + (size_t)t*16*4096);
            oacc[t][0] = mfma_pv(vf, pb0, oacc[t][0]);
            oacc[t][1] = mfma_pv(vf, pb1, oacc[t][1]);
        }
    }

    // ---- rowsum: sum over quads in-wave, partials per wave to LDS ----
    #pragma unroll
    for(int rg=0; rg<2; rg++){
        float v = rsum[rg];
        v += __shfl_xor(v, 16);
        v += __shfl_xor(v, 32);
        if(quad == 0) sRS[w][16*rg + lq] = v;
    }
    __syncthreads();

    // ---- O reduction across waves, 4 rounds of 64 h-rows ----
    for(int c=0; c<4; c++){
        if(c) __syncthreads();
        #pragma unroll
        for(int tt=0; tt<4; tt++){
            int t = 4*c + tt;
            #pragma unroll
            for(int rg=0; rg<2; rg++){
                #pragma unroll
                for(int r=0; r<4; r++)
                    sRed[w][(16*rg+lq)*65 + 16*tt + 4*quad + r] = oacc[t][rg][r];
            }
        }
        __syncthreads();
        #pragma unroll
        for(int j=0; j<8; j++){
            int idx = j*256 + tid;
            int hl = idx & 63, q = idx >> 6;
            float s  = sRed[0][q*65+hl] + sRed[1][q*65+hl]
                     + sRed[2][q*65+hl] + sRed[3][q*65+hl];
            float rs = sRS[0][q] + sRS[1][q] + sRS[2][q] + sRS[3][q];
            out[((size_t)(b*4096 + qbase + q))*256 + 64*c + hl] = s / rs;
        }
    }
}

extern "C" void kernel_launch(void* const* d_in, const int* in_sizes, int n_in,
                              void* d_out, int out_size, void* d_ws, size_t ws_size,
                              hipStream_t stream){
    (void)in_sizes; (void)n_in; (void)out_size;
    const float* x1 = (const float*)d_in[0];
    const float* x2 = (const float*)d_in[1];
    const int*   mk = (const int*)  d_in[2];
    const float* Wq = (const float*)d_in[3];
    const float* bq = (const float*)d_in[4];
    const float* Wk = (const float*)d_in[5];
    const float* bk = (const float*)d_in[6];
    const float* Wv = (const float*)d_in[7];
    const float* bv = (const float*)d_in[8];
    float* out = (float*)d_out;
    char* ws = (char*)d_ws;

    // ws layout: wt 384K @0 | q 8M | k... | vt...
    unsigned short* wt = (unsigned short*)ws;
    unsigned short* qb = (unsigned short*)(ws + 393216);
    const size_t kvoff = 393216 + 8388608;

    wt_prep<<<dim3(256,3), 256, 0, stream>>>(Wq, Wk, Wv, wt);
    proj_q <<<256, 256, 0, stream>>>(x1, wt, bq, qb);

    if(ws_size >= kvoff + 16ull*1024*1024){
        unsigned short* kbuf = (unsigned short*)(ws + kvoff);
        unsigned short* vtbf = (unsigned short*)(ws + kvoff + 8388608);
        for(int b=0;b<4;b++)
            proj_kv<<<dim3(64,2), 256, 0, stream>>>(x2, wt, bk, bv,
                    kbuf + (size_t)b*1048576, vtbf + (size_t)b*1048576, b);
        attn<<<dim3(128,4), 256, 0, stream>>>(qb, kbuf, vtbf, mk, out, 0);
    } else {
        unsigned short* kbuf = (unsigned short*)(ws + kvoff);
        unsigned short* vtbf = (unsigned short*)(ws + kvoff + 2097152);
        for(int b=0;b<4;b++){
            proj_kv<<<dim3(64,2), 256, 0, stream>>>(x2, wt, bk, bv, kbuf, vtbf, b);
            attn<<<dim3(128,1), 256, 0, stream>>>(qb, kbuf, vtbf, mk, out, b);
        }
    }
}

// Round 9
// 616.138 us; speedup vs baseline: 1.3552x; 1.3072x over previous
//
#include <hip/hip_runtime.h>

typedef float  f32x4 __attribute__((ext_vector_type(4)));
typedef short  s16x8 __attribute__((ext_vector_type(8)));
typedef short  s16x4 __attribute__((ext_vector_type(4)));

#define MFMA16(a,b,c) __builtin_amdgcn_mfma_f32_16x16x32_bf16(a,b,c,0,0,0)

static __device__ __forceinline__ f32x4 mfma_pv(s16x4 a, s16x4 b, f32x4 c){
#if defined(__HIP_DEVICE_COMPILE__)
    return __builtin_amdgcn_mfma_f32_16x16x16bf16_1k(a, b, c, 0, 0, 0);
#else
    (void)a; (void)b; return c;
#endif
}

// B=4, N1=N2=4096, D=H=256. Inputs fp32, output fp32.
static __device__ __forceinline__ unsigned short f2bf(float f){
    union { float f; unsigned int u; } x; x.f = f;
    unsigned int r = x.u + 0x7fffu + ((x.u >> 16) & 1u);   // RNE
    return (unsigned short)(r >> 16);
}

// ---------------- kernel 1: W^T -> bf16 ----------------
__global__ void wt_prep(const float* __restrict__ Wq, const float* __restrict__ Wk,
                        const float* __restrict__ Wv, unsigned short* __restrict__ wt){
    int n = blockIdx.x, p = blockIdx.y, k = threadIdx.x;
    const float* W = (p==0) ? Wq : ((p==1) ? Wk : Wv);
    wt[p*65536 + n*256 + k] = f2bf(W[k*256 + n]);
}

// -------- staging helper: x tile (64x256 fp32) -> bf16 LDS (stride 264) ------
static __device__ __forceinline__ void stage_x(const float* x, size_t row0,
                                               int tid, unsigned short* sX){
    const float* xg = x + row0*256;
    #pragma unroll
    for(int rr=0; rr<16; rr++){
        int c = tid + rr*256;
        int row = c>>6, cc = c&63;
        float4 f = *(const float4*)(xg + row*256 + cc*4);
        unsigned short* d = &sX[row*264 + cc*4];
        d[0]=f2bf(f.x); d[1]=f2bf(f.y); d[2]=f2bf(f.z); d[3]=f2bf(f.w);
    }
}

// ---------------- kernel 2: ALL projections, one launch ----------------------
// grid (64 row-tiles, 3 proj, nb batches), 256 threads (4 waves).
// p=0: Q row-major (all batches via z). p=1: K -> kfrag (MFMA A-frag order,
// LDS round-trip). p=2: V -> vfrag (PV A-frag order, DIRECT from C-layout regs:
// C row = 4*quad+r == frag j=r, so each thread already holds its frag elems).
// frag layouts (shorts): [((kt*4 + w)*8 + i)*64 + lane]*8  (i = ks for K, t2
// for V; V packs t=2*t2 in o[0..3], t=2*t2+1 in o[4..7]). 2MB per batch each.
__global__ __launch_bounds__(256) void proj_all(const float* __restrict__ x1,
        const float* __restrict__ x2, const unsigned short* __restrict__ wt,
        const float* __restrict__ bq, const float* __restrict__ bk,
        const float* __restrict__ bv, int b0,
        unsigned short* __restrict__ qdst, unsigned short* __restrict__ kfrag,
        unsigned short* __restrict__ vfrag){
    const int rt = blockIdx.x, p = blockIdx.y, z = blockIdx.z;
    const int zz = b0 + z;
    const int tid = threadIdx.x, w = tid>>6, lane = tid&63, quad = lane>>4, lq = lane&15;
    __shared__ __align__(16) unsigned short sX[64*264];

    const float* x = (p==0) ? x1 : x2;
    stage_x(x, (size_t)(zz*64 + rt)*64, tid, sX);
    __syncthreads();

    s16x8 a[8];
    #pragma unroll
    for(int ks=0; ks<8; ks++)
        a[ks] = *(const s16x8*)(&sX[(16*w+lq)*264 + ks*32 + quad*8]);

    f32x4 acc[16];
    #pragma unroll
    for(int t=0;t<16;t++) acc[t] = (f32x4)(0.0f);
    const unsigned short* wtp = wt + p*65536;
    #pragma unroll
    for(int ks=0; ks<8; ks++){
        #pragma unroll
        for(int t=0; t<16; t++){
            s16x8 bf_ = *(const s16x8*)(wtp + (16*t+lq)*256 + ks*32 + quad*8);
            acc[t] = MFMA16(a[ks], bf_, acc[t]);
        }
    }

    if(p == 0){          // Q row-major
        #pragma unroll
        for(int t=0;t<16;t++){
            float bvf = bq[16*t+lq];
            #pragma unroll
            for(int r=0;r<4;r++){
                size_t row = (size_t)(zz*64 + rt)*64 + 16*w + 4*quad + r;
                qdst[row*256 + 16*t + lq] = f2bf(acc[t][r] + bvf);
            }
        }
    } else if(p == 1){   // K -> kfrag via LDS round-trip
        __syncthreads();                      // all waves done reading sX
        #pragma unroll
        for(int t=0;t<16;t++){
            float bvf = bk[16*t+lq];
            #pragma unroll
            for(int r=0;r<4;r++)
                sX[(16*w + 4*quad + r)*264 + 16*t + lq] = f2bf(acc[t][r] + bvf);
        }
        __syncthreads();
        unsigned short* kd = kfrag + (size_t)z*1048576;
        #pragma unroll
        for(int ks=0; ks<8; ks++){
            s16x8 v = *(const s16x8*)(&sX[(16*w + lq)*264 + 32*ks + 8*quad]);
            *(s16x8*)(kd + ((((size_t)rt*4 + w)*8 + ks)*64 + lane)*8) = v;
        }
    } else {             // V -> vfrag direct (coalesced 1KB per instr)
        unsigned short* vd = vfrag + (size_t)z*1048576;
        #pragma unroll
        for(int t2=0; t2<8; t2++){
            float b0f = bv[16*(2*t2  )+lq];
            float b1f = bv[16*(2*t2+1)+lq];
            s16x8 o;
            #pragma unroll
            for(int r=0;r<4;r++){
                o[r]   = (short)f2bf(acc[2*t2  ][r] + b0f);
                o[4+r] = (short)f2bf(acc[2*t2+1][r] + b1f);
            }
            *(s16x8*)(vd + ((((size_t)rt*4 + w)*8 + t2)*64 + lane)*8) = o;
        }
    }
}

// ---------------- kernel 3: barrier-free flash attn, frag-coalesced ----------
// 512 threads = 8 waves: qg = wave>>2 (q-half), w = wave&3 (n2 slice of 16).
// TM=64 q-rows/block, grid 256 (single-shot, XCD-swizzled) or 64 (per-batch).
// Main loop: all global loads are contiguous coalesced wave-blocks (kfrag/
// vfrag) or 64B-row mask int4s. Zero barriers/LDS until the epilogue.
__global__ __launch_bounds__(512,2) void attn(
        const unsigned short* __restrict__ qb, const unsigned short* __restrict__ kfrag,
        const unsigned short* __restrict__ vfrag, const int* __restrict__ mask,
        float* __restrict__ out, int b0){
    const int bid = blockIdx.x;
    int b, qt, bk_;
    if(gridDim.x == 256){ b = (bid&7)>>1; qt = (bid>>3)*2 + (bid&1); bk_ = b; }
    else                { b = b0; qt = bid; bk_ = 0; }
    const int tid = threadIdx.x, w4 = tid>>6, lane = tid&63, quad = lane>>4, lq = lane&15;
    const int qg = w4>>2, w = w4&3;
    const int qbase = qt*64 + 32*qg;

    __shared__ float sRS[2][4][32];
    __shared__ float sRed[4][32*65 + 1];

    // Q as B-operand frags (rows qbase+16rg+lq)
    s16x8 qf[2][8];
    #pragma unroll
    for(int rg=0; rg<2; rg++){
        size_t row = (size_t)(b*4096 + qbase + 16*rg + lq);
        #pragma unroll
        for(int ks=0; ks<8; ks++)
            qf[rg][ks] = *(const s16x8*)(qb + row*256 + ks*32 + quad*8);
    }

    f32x4 oacc[16][2];                 // O^T partial: h=16t+4quad+r, q=16rg+lq
    #pragma unroll
    for(int t=0;t<16;t++){ oacc[t][0] = (f32x4)(0.0f); oacc[t][1] = (f32x4)(0.0f); }
    float rsum[2] = {0.0f, 0.0f};

    const unsigned short* kfb = kfrag + (size_t)bk_*1048576;
    const unsigned short* vfb = vfrag + (size_t)bk_*1048576;
    const int* mp0 = mask + ((size_t)(b*4096 + qbase) + lq)*4096 + 16*w + 4*quad;

    for(int kt=0; kt<64; kt++){
        const size_t fb = ((size_t)kt*4 + w)*8*64*8;
        // K frags: 8 coalesced 1KB loads
        s16x8 kf[8];
        #pragma unroll
        for(int ks=0; ks<8; ks++)
            kf[ks] = *(const s16x8*)(kfb + fb + ((size_t)ks*64 + lane)*8);
        // mask: 2 int4 loads (64B/row, halves shared with neighbor waves)
        int4 m0 = *(const int4*)(mp0 + (size_t)kt*64);
        int4 m1 = *(const int4*)(mp0 + (size_t)16*4096 + kt*64);
        // S^T: D[n2local=4quad+r][q=lq]
        f32x4 sacc0 = (f32x4)(0.0f), sacc1 = (f32x4)(0.0f);
        #pragma unroll
        for(int ks=0; ks<8; ks++){
            sacc0 = MFMA16(kf[ks], qf[0][ks], sacc0);
            sacc1 = MFMA16(kf[ks], qf[1][ks], sacc1);
        }
        // mask + exp + pack (C rows 4quad+r == PV k=4quad+j)
        s16x4 pb0, pb1;
        {
            float p;
            p = (m0.x>0)?__expf(sacc0[0]*0.0625f):1.0f; rsum[0]+=p; pb0[0]=(short)f2bf(p);
            p = (m0.y>0)?__expf(sacc0[1]*0.0625f):1.0f; rsum[0]+=p; pb0[1]=(short)f2bf(p);
            p = (m0.z>0)?__expf(sacc0[2]*0.0625f):1.0f; rsum[0]+=p; pb0[2]=(short)f2bf(p);
            p = (m0.w>0)?__expf(sacc0[3]*0.0625f):1.0f; rsum[0]+=p; pb0[3]=(short)f2bf(p);
            p = (m1.x>0)?__expf(sacc1[0]*0.0625f):1.0f; rsum[1]+=p; pb1[0]=(short)f2bf(p);
            p = (m1.y>0)?__expf(sacc1[1]*0.0625f):1.0f; rsum[1]+=p; pb1[1]=(short)f2bf(p);
            p = (m1.z>0)?__expf(sacc1[2]*0.0625f):1.0f; rsum[1]+=p; pb1[2]=(short)f2bf(p);
            p = (m1.w>0)?__expf(sacc1[3]*0.0625f):1.0f; rsum[1]+=p; pb1[3]=(short)f2bf(p);
        }
        // PV: V frags, 8 coalesced 1KB loads (two t's each)
        #pragma unroll
        for(int t2=0; t2<8; t2++){
            s16x8 vv = *(const s16x8*)(vfb + fb + ((size_t)t2*64 + lane)*8);
            s16x4 vlo = __builtin_shufflevector(vv, vv, 0,1,2,3);
            s16x4 vhi = __builtin_shufflevector(vv, vv, 4,5,6,7);
            oacc[2*t2  ][0] = mfma_pv(vlo, pb0, oacc[2*t2  ][0]);
            oacc[2*t2  ][1] = mfma_pv(vlo, pb1, oacc[2*t2  ][1]);
            oacc[2*t2+1][0] = mfma_pv(vhi, pb0, oacc[2*t2+1][0]);
            oacc[2*t2+1][1] = mfma_pv(vhi, pb1, oacc[2*t2+1][1]);
        }
    }

    // ---- rowsum partials ----
    #pragma unroll
    for(int rg=0; rg<2; rg++){
        float v = rsum[rg];
        v += __shfl_xor(v, 16);
        v += __shfl_xor(v, 32);
        if(quad == 0) sRS[qg][w][16*rg + lq] = v;
    }

    // ---- O reduction: 2 q-groups x 4 h-chunks of 64 ----
    for(int g=0; g<2; g++){
        for(int c=0; c<4; c++){
            __syncthreads();
            if(qg == g){
                #pragma unroll
                for(int tt=0; tt<4; tt++){
                    int t = 4*c + tt;
                    #pragma unroll
                    for(int rg=0; rg<2; rg++){
                        #pragma unroll
                        for(int r=0; r<4; r++)
                            sRed[w][(16*rg+lq)*65 + 16*tt + 4*quad + r] = oacc[t][rg][r];
                    }
                }
            }
            __syncthreads();
            #pragma unroll
            for(int j=0; j<4; j++){
                int idx = j*512 + tid;
                int hl = idx & 63, q = idx >> 6;     // q 0..31 (local to group g)
                float s  = sRed[0][q*65+hl] + sRed[1][q*65+hl]
                         + sRed[2][q*65+hl] + sRed[3][q*65+hl];
                float rs = sRS[g][0][q] + sRS[g][1][q] + sRS[g][2][q] + sRS[g][3][q];
                out[((size_t)(b*4096 + qt*64 + 32*g + q))*256 + 64*c + hl] = s / rs;
            }
        }
    }
}

extern "C" void kernel_launch(void* const* d_in, const int* in_sizes, int n_in,
                              void* d_out, int out_size, void* d_ws, size_t ws_size,
                              hipStream_t stream){
    (void)in_sizes; (void)n_in; (void)out_size;
    const float* x1 = (const float*)d_in[0];
    const float* x2 = (const float*)d_in[1];
    const int*   mk = (const int*)  d_in[2];
    const float* Wq = (const float*)d_in[3];
    const float* bq = (const float*)d_in[4];
    const float* Wk = (const float*)d_in[5];
    const float* bk = (const float*)d_in[6];
    const float* Wv = (const float*)d_in[7];
    const float* bv = (const float*)d_in[8];
    float* out = (float*)d_out;
    char* ws = (char*)d_ws;

    // ws layout: wt 384K @0 | q 8M | kfrag | vfrag
    unsigned short* wt = (unsigned short*)ws;
    unsigned short* qb = (unsigned short*)(ws + 393216);
    const size_t kvoff = 393216 + 8388608;          // 8781824 (16B aligned)

    wt_prep<<<dim3(256,3), 256, 0, stream>>>(Wq, Wk, Wv, wt);

    if(ws_size >= kvoff + 16ull*1024*1024){
        unsigned short* kf = (unsigned short*)(ws + kvoff);
        unsigned short* vf = (unsigned short*)(ws + kvoff + 8388608);
        proj_all<<<dim3(64,3,4), 256, 0, stream>>>(x1, x2, wt, bq, bk, bv, 0,
                                                   qb, kf, vf);
        attn<<<256, 512, 0, stream>>>(qb, kf, vf, mk, out, 0);
    } else {
        unsigned short* kf = (unsigned short*)(ws + kvoff);
        unsigned short* vf = (unsigned short*)(ws + kvoff + 2097152);
        for(int b=0;b<4;b++){
            proj_all<<<dim3(64,3,1), 256, 0, stream>>>(x1, x2, wt, bq, bk, bv, b,
                                                       qb, kf, vf);
            attn<<<64, 512, 0, stream>>>(qb, kf, vf, mk, out, b);
        }
    }
}

// Round 10
// 563.495 us; speedup vs baseline: 1.4819x; 1.0934x over previous
//
#include <hip/hip_runtime.h>

typedef float  f32x4 __attribute__((ext_vector_type(4)));
typedef short  s16x8 __attribute__((ext_vector_type(8)));
typedef short  s16x4 __attribute__((ext_vector_type(4)));

#define MFMA16(a,b,c) __builtin_amdgcn_mfma_f32_16x16x32_bf16(a,b,c,0,0,0)

static __device__ __forceinline__ f32x4 mfma_pv(s16x4 a, s16x4 b, f32x4 c){
#if defined(__HIP_DEVICE_COMPILE__)
    return __builtin_amdgcn_mfma_f32_16x16x16bf16_1k(a, b, c, 0, 0, 0);
#else
    (void)a; (void)b; return c;
#endif
}

// async global->LDS, 16B per lane: data lands at lds_base(wave-uniform)+lane*16
static __device__ __forceinline__ void glds16(const void* g, void* l){
#if defined(__HIP_DEVICE_COMPILE__)
    __builtin_amdgcn_global_load_lds(
        (const __attribute__((address_space(1))) unsigned int*)g,
        (__attribute__((address_space(3))) unsigned int*)l, 16, 0, 0);
#else
    (void)g; (void)l;
#endif
}

// B=4, N1=N2=4096, D=H=256. Inputs fp32, output fp32.
static __device__ __forceinline__ unsigned short f2bf(float f){
    union { float f; unsigned int u; } x; x.f = f;
    unsigned int r = x.u + 0x7fffu + ((x.u >> 16) & 1u);   // RNE
    return (unsigned short)(r >> 16);
}

// ---------------- kernel 1: W^T -> bf16 ----------------
__global__ void wt_prep(const float* __restrict__ Wq, const float* __restrict__ Wk,
                        const float* __restrict__ Wv, unsigned short* __restrict__ wt){
    int n = blockIdx.x, p = blockIdx.y, k = threadIdx.x;
    const float* W = (p==0) ? Wq : ((p==1) ? Wk : Wv);
    wt[p*65536 + n*256 + k] = f2bf(W[k*256 + n]);
}

// -------- staging helper: x tile (64x256 fp32) -> bf16 LDS (stride 264) ------
static __device__ __forceinline__ void stage_x(const float* x, size_t row0,
                                               int tid, unsigned short* sX){
    const float* xg = x + row0*256;
    #pragma unroll
    for(int rr=0; rr<16; rr++){
        int c = tid + rr*256;
        int row = c>>6, cc = c&63;
        float4 f = *(const float4*)(xg + row*256 + cc*4);
        unsigned short* d = &sX[row*264 + cc*4];
        d[0]=f2bf(f.x); d[1]=f2bf(f.y); d[2]=f2bf(f.z); d[3]=f2bf(f.w);
    }
}

// ---------------- kernel 2: ALL projections, one launch ----------------------
// p=0: Q row-major. p=1: K -> kfrag (MFMA A-frag order, LDS round-trip).
// p=2: V -> vfrag (PV A-frag order, direct from C-layout regs).
// frag layouts (shorts): [((kt*4 + w)*8 + i)*64 + lane]*8 ; 32KB per kt block.
__global__ __launch_bounds__(256) void proj_all(const float* __restrict__ x1,
        const float* __restrict__ x2, const unsigned short* __restrict__ wt,
        const float* __restrict__ bq, const float* __restrict__ bk,
        const float* __restrict__ bv, int b0,
        unsigned short* __restrict__ qdst, unsigned short* __restrict__ kfrag,
        unsigned short* __restrict__ vfrag){
    const int rt = blockIdx.x, p = blockIdx.y, z = blockIdx.z;
    const int zz = b0 + z;
    const int tid = threadIdx.x, w = tid>>6, lane = tid&63, quad = lane>>4, lq = lane&15;
    __shared__ __align__(16) unsigned short sX[64*264];

    const float* x = (p==0) ? x1 : x2;
    stage_x(x, (size_t)(zz*64 + rt)*64, tid, sX);
    __syncthreads();

    s16x8 a[8];
    #pragma unroll
    for(int ks=0; ks<8; ks++)
        a[ks] = *(const s16x8*)(&sX[(16*w+lq)*264 + ks*32 + quad*8]);

    f32x4 acc[16];
    #pragma unroll
    for(int t=0;t<16;t++) acc[t] = (f32x4)(0.0f);
    const unsigned short* wtp = wt + p*65536;
    #pragma unroll
    for(int ks=0; ks<8; ks++){
        #pragma unroll
        for(int t=0; t<16; t++){
            s16x8 bf_ = *(const s16x8*)(wtp + (16*t+lq)*256 + ks*32 + quad*8);
            acc[t] = MFMA16(a[ks], bf_, acc[t]);
        }
    }

    if(p == 0){          // Q row-major
        #pragma unroll
        for(int t=0;t<16;t++){
            float bvf = bq[16*t+lq];
            #pragma unroll
            for(int r=0;r<4;r++){
                size_t row = (size_t)(zz*64 + rt)*64 + 16*w + 4*quad + r;
                qdst[row*256 + 16*t + lq] = f2bf(acc[t][r] + bvf);
            }
        }
    } else if(p == 1){   // K -> kfrag via LDS round-trip
        __syncthreads();
        #pragma unroll
        for(int t=0;t<16;t++){
            float bvf = bk[16*t+lq];
            #pragma unroll
            for(int r=0;r<4;r++)
                sX[(16*w + 4*quad + r)*264 + 16*t + lq] = f2bf(acc[t][r] + bvf);
        }
        __syncthreads();
        unsigned short* kd = kfrag + (size_t)z*1048576;
        #pragma unroll
        for(int ks=0; ks<8; ks++){
            s16x8 v = *(const s16x8*)(&sX[(16*w + lq)*264 + 32*ks + 8*quad]);
            *(s16x8*)(kd + ((((size_t)rt*4 + w)*8 + ks)*64 + lane)*8) = v;
        }
    } else {             // V -> vfrag direct
        unsigned short* vd = vfrag + (size_t)z*1048576;
        #pragma unroll
        for(int t2=0; t2<8; t2++){
            float b0f = bv[16*(2*t2  )+lq];
            float b1f = bv[16*(2*t2+1)+lq];
            s16x8 o;
            #pragma unroll
            for(int r=0;r<4;r++){
                o[r]   = (short)f2bf(acc[2*t2  ][r] + b0f);
                o[4+r] = (short)f2bf(acc[2*t2+1][r] + b1f);
            }
            *(s16x8*)(vd + ((((size_t)rt*4 + w)*8 + t2)*64 + lane)*8) = o;
        }
    }
}

// ---------------- kernel 3: flash attn, async-LDS double-buffered ------------
// 512 threads = 8 waves (qg = wave>>2, w = wave&3). TM=64 q-rows/block.
// LDS: 2 x 64KB buffers (K 32KB + V 32KB, frag order). Per iter: one barrier
// (vmcnt(0) drain = the pacing), compute from buf[cb], then fire-and-forget
// stage(kt+1 -> buf[cb^1]) + mask prefetch at body END (after last ds_read,
// so no conservative alias-wait lands before compute). Epilogue LDS aliases
// buffer 0 (safe: buf0 last read at kt=62, all waves past kt=63's barrier).
__global__ __launch_bounds__(512,2) void attn(
        const unsigned short* __restrict__ qb, const unsigned short* __restrict__ kfrag,
        const unsigned short* __restrict__ vfrag, const int* __restrict__ mask,
        float* __restrict__ out, int b0){
    const int bid = blockIdx.x;
    int b, qt, bk_;
    if(gridDim.x == 256){ b = (bid&7)>>1; qt = (bid>>3)*2 + (bid&1); bk_ = b; }
    else                { b = b0; qt = bid; bk_ = 0; }
    const int tid = threadIdx.x, w4 = tid>>6, lane = tid&63, quad = lane>>4, lq = lane&15;
    const int qg = w4>>2, w = w4&3;
    const int qbase = qt*64 + 32*qg;

    __shared__ __align__(16) unsigned char smem[131072];

    // Q as B-operand frags (rows qbase+16rg+lq)
    s16x8 qf[2][8];
    #pragma unroll
    for(int rg=0; rg<2; rg++){
        size_t row = (size_t)(b*4096 + qbase + 16*rg + lq);
        #pragma unroll
        for(int ks=0; ks<8; ks++)
            qf[rg][ks] = *(const s16x8*)(qb + row*256 + ks*32 + quad*8);
    }

    f32x4 oacc[16][2];                 // O^T partial: h=16t+4quad+r, q=16rg+lq
    #pragma unroll
    for(int t=0;t<16;t++){ oacc[t][0] = (f32x4)(0.0f); oacc[t][1] = (f32x4)(0.0f); }
    float rsum[2] = {0.0f, 0.0f};

    const unsigned char* kfb = (const unsigned char*)(kfrag + (size_t)bk_*1048576);
    const unsigned char* vfb = (const unsigned char*)(vfrag + (size_t)bk_*1048576);
    const int* mp0 = mask + ((size_t)(b*4096 + qbase) + lq)*4096 + 16*w + 4*quad;
    const unsigned lsl = w4*1024 + lane*16;   // per-lane global offset within 8KB round
    const unsigned ldd = w4*1024;             // wave-uniform LDS offset

    // prologue: stage kt=0 into buf0, prefetch mask kt=0
    #pragma unroll
    for(int r=0; r<4; r++){
        glds16(kfb + r*8192 + lsl, smem + r*8192 + ldd);
        glds16(vfb + r*8192 + lsl, smem + 32768 + r*8192 + ldd);
    }
    int4 mA0 = *(const int4*)(mp0);
    int4 mA1 = *(const int4*)(mp0 + (size_t)16*4096);

    for(int kt=0; kt<64; kt++){
        const int cb = kt & 1;
        __syncthreads();   // drains prev staging + mask prefetch (vmcnt(0))
        const unsigned short* bK = (const unsigned short*)(smem + cb*65536);
        const unsigned short* bV = (const unsigned short*)(smem + cb*65536 + 32768);

        // ---- S^T: D[n2local=4quad+r][q=lq] ----
        f32x4 sacc0 = (f32x4)(0.0f), sacc1 = (f32x4)(0.0f);
        #pragma unroll
        for(int ks=0; ks<8; ks++){
            s16x8 kf = *(const s16x8*)(bK + ((w*8 + ks)*64 + lane)*8);
            sacc0 = MFMA16(kf, qf[0][ks], sacc0);
            sacc1 = MFMA16(kf, qf[1][ks], sacc1);
        }
        // ---- mask + exp + pack (C rows 4quad+r == PV k=4quad+j) ----
        s16x4 pb0, pb1;
        {
            float p;
            p = (mA0.x>0)?__expf(sacc0[0]*0.0625f):1.0f; rsum[0]+=p; pb0[0]=(short)f2bf(p);
            p = (mA0.y>0)?__expf(sacc0[1]*0.0625f):1.0f; rsum[0]+=p; pb0[1]=(short)f2bf(p);
            p = (mA0.z>0)?__expf(sacc0[2]*0.0625f):1.0f; rsum[0]+=p; pb0[2]=(short)f2bf(p);
            p = (mA0.w>0)?__expf(sacc0[3]*0.0625f):1.0f; rsum[0]+=p; pb0[3]=(short)f2bf(p);
            p = (mA1.x>0)?__expf(sacc1[0]*0.0625f):1.0f; rsum[1]+=p; pb1[0]=(short)f2bf(p);
            p = (mA1.y>0)?__expf(sacc1[1]*0.0625f):1.0f; rsum[1]+=p; pb1[1]=(short)f2bf(p);
            p = (mA1.z>0)?__expf(sacc1[2]*0.0625f):1.0f; rsum[1]+=p; pb1[2]=(short)f2bf(p);
            p = (mA1.w>0)?__expf(sacc1[3]*0.0625f):1.0f; rsum[1]+=p; pb1[3]=(short)f2bf(p);
        }
        // ---- PV ----
        #pragma unroll
        for(int t2=0; t2<8; t2++){
            s16x8 vv = *(const s16x8*)(bV + ((w*8 + t2)*64 + lane)*8);
            s16x4 vlo = __builtin_shufflevector(vv, vv, 0,1,2,3);
            s16x4 vhi = __builtin_shufflevector(vv, vv, 4,5,6,7);
            oacc[2*t2  ][0] = mfma_pv(vlo, pb0, oacc[2*t2  ][0]);
            oacc[2*t2  ][1] = mfma_pv(vlo, pb1, oacc[2*t2  ][1]);
            oacc[2*t2+1][0] = mfma_pv(vhi, pb0, oacc[2*t2+1][0]);
            oacc[2*t2+1][1] = mfma_pv(vhi, pb1, oacc[2*t2+1][1]);
        }
        // ---- stage kt+1 into the other buffer + prefetch next mask ----
        if(kt < 63){
            const unsigned char* gK = kfb + (size_t)(kt+1)*32768;
            const unsigned char* gV = vfb + (size_t)(kt+1)*32768;
            unsigned char* dst = smem + (cb^1)*65536;
            #pragma unroll
            for(int r=0; r<4; r++){
                glds16(gK + r*8192 + lsl, dst + r*8192 + ldd);
                glds16(gV + r*8192 + lsl, dst + 32768 + r*8192 + ldd);
            }
            mA0 = *(const int4*)(mp0 + (size_t)(kt+1)*64);
            mA1 = *(const int4*)(mp0 + (size_t)16*4096 + (kt+1)*64);
        }
    }

    // ---- epilogue: alias buf0 region (safe; see header comment) ----
    float* sRS  = (float*)smem;              // [8][32]
    float* sRed = (float*)(smem + 1024);     // [4][2081]
    #pragma unroll
    for(int rg=0; rg<2; rg++){
        float v = rsum[rg];
        v += __shfl_xor(v, 16);
        v += __shfl_xor(v, 32);
        if(quad == 0) sRS[(qg*4 + w)*32 + 16*rg + lq] = v;
    }
    for(int g=0; g<2; g++){
        for(int c=0; c<4; c++){
            __syncthreads();
            if(qg == g){
                #pragma unroll
                for(int tt=0; tt<4; tt++){
                    int t = 4*c + tt;
                    #pragma unroll
                    for(int rg=0; rg<2; rg++){
                        #pragma unroll
                        for(int r=0; r<4; r++)
                            sRed[w*2081 + (16*rg+lq)*65 + 16*tt + 4*quad + r] = oacc[t][rg][r];
                    }
                }
            }
            __syncthreads();
            #pragma unroll
            for(int j=0; j<4; j++){
                int idx = j*512 + tid;
                int hl = idx & 63, q = idx >> 6;
                float s  = sRed[0*2081 + q*65+hl] + sRed[1*2081 + q*65+hl]
                         + sRed[2*2081 + q*65+hl] + sRed[3*2081 + q*65+hl];
                float rs = sRS[(g*4+0)*32+q] + sRS[(g*4+1)*32+q]
                         + sRS[(g*4+2)*32+q] + sRS[(g*4+3)*32+q];
                out[((size_t)(b*4096 + qt*64 + 32*g + q))*256 + 64*c + hl] = s / rs;
            }
        }
    }
}

extern "C" void kernel_launch(void* const* d_in, const int* in_sizes, int n_in,
                              void* d_out, int out_size, void* d_ws, size_t ws_size,
                              hipStream_t stream){
    (void)in_sizes; (void)n_in; (void)out_size;
    const float* x1 = (const float*)d_in[0];
    const float* x2 = (const float*)d_in[1];
    const int*   mk = (const int*)  d_in[2];
    const float* Wq = (const float*)d_in[3];
    const float* bq = (const float*)d_in[4];
    const float* Wk = (const float*)d_in[5];
    const float* bk = (const float*)d_in[6];
    const float* Wv = (const float*)d_in[7];
    const float* bv = (const float*)d_in[8];
    float* out = (float*)d_out;
    char* ws = (char*)d_ws;

    // ws layout: wt 384K @0 | q 8M | kfrag | vfrag
    unsigned short* wt = (unsigned short*)ws;
    unsigned short* qb = (unsigned short*)(ws + 393216);
    const size_t kvoff = 393216 + 8388608;

    wt_prep<<<dim3(256,3), 256, 0, stream>>>(Wq, Wk, Wv, wt);

    if(ws_size >= kvoff + 16ull*1024*1024){
        unsigned short* kf = (unsigned short*)(ws + kvoff);
        unsigned short* vf = (unsigned short*)(ws + kvoff + 8388608);
        proj_all<<<dim3(64,3,4), 256, 0, stream>>>(x1, x2, wt, bq, bk, bv, 0,
                                                   qb, kf, vf);
        attn<<<256, 512, 0, stream>>>(qb, kf, vf, mk, out, 0);
    } else {
        unsigned short* kf = (unsigned short*)(ws + kvoff);
        unsigned short* vf = (unsigned short*)(ws + kvoff + 2097152);
        for(int b=0;b<4;b++){
            proj_all<<<dim3(64,3,1), 256, 0, stream>>>(x1, x2, wt, bq, bk, bv, b,
                                                       qb, kf, vf);
            attn<<<64, 512, 0, stream>>>(qb, kf, vf, mk, out, b);
        }
    }
}